// Round 8
// baseline (103.102 us; speedup 1.0000x reference)
//
#include <hip/hip_runtime.h>

// Problem constants
#define B_     64
#define L_     1024
#define D_     1280   // 320 float4
#define H1_    640
#define H2_    320
#define NSPLIT 32     // per-batch even-split stripes for pooling

// ---------------- Kernel 1: per-batch even-split stripe partial sums ----------------
// BYTE-IDENTICAL to R7. Launched TWICE this round as a timing probe:
// dur_delta vs R7 == this kernel's duration (it's a pure function of inputs,
// so the duplicate write is deterministic and output-invariant).
__global__ void pool_partial(const float* __restrict__ rep, const int* __restrict__ blen,
                             float* __restrict__ part) {
    const int s   = blockIdx.x;     // stripe
    const int b   = blockIdx.y;     // batch
    const int tid = threadIdx.x;    // 0..319 (float4 lane)
    const int n   = blen[b] - 2;    // valid rows (>=1)

    const int l0 = 1 + (s * n) / NSPLIT;
    const int l1 = 1 + ((s + 1) * n) / NSPLIT;

    float4 acc = make_float4(0.f, 0.f, 0.f, 0.f);
    const float4* base = (const float4*)rep + (size_t)b * L_ * (D_ / 4) + tid;
    #pragma unroll 8
    for (int l = l0; l < l1; ++l) {
        float4 v = base[(size_t)l * (D_ / 4)];
        acc.x += v.x; acc.y += v.y; acc.z += v.z; acc.w += v.w;
    }
    // always write (empty stripes contribute zeros)
    ((float4*)part)[((size_t)b * NSPLIT + s) * (D_ / 4) + tid] = acc;
}

// ---------------- Kernel 2: per-batch fused tail (BYTE-IDENTICAL to R7) ----------
__global__ void fused_tail(const float* __restrict__ part, const int* __restrict__ blen,
                           const float* __restrict__ W1, const float* __restrict__ b1,
                           const float* __restrict__ W2, const float* __restrict__ b2,
                           const float* __restrict__ W3, const float* __restrict__ b3,
                           float* __restrict__ out) {
    const int b   = blockIdx.x;
    const int tid = threadIdx.x;   // 0..319

    __shared__ float prow[D_];     // 5 KB
    __shared__ float hrow[H1_];    // 2.5 KB
    __shared__ float erow[H2_];    // 1.25 KB

    // ---- Phase A: stripe reduce; thread owns float4 column tid ----
    {
        int n = blen[b] - 2; if (n < 1) n = 1;
        const float inv = 1.0f / (float)n;
        const float4* p = (const float4*)part + (size_t)b * NSPLIT * (D_ / 4) + tid;
        float4 a = make_float4(0.f, 0.f, 0.f, 0.f);
        #pragma unroll
        for (int s = 0; s < NSPLIT; ++s) {
            float4 v = p[(size_t)s * (D_ / 4)];
            a.x += v.x; a.y += v.y; a.z += v.z; a.w += v.w;
        }
        ((float4*)prow)[tid] = make_float4(a.x * inv, a.y * inv, a.z * inv, a.w * inv);
    }
    __syncthreads();

    // ---- Phase B: hrow = relu(prow @ W1 + b1); thread owns cols tid, tid+320 ----
    {
        const int j1 = tid, j2 = tid + 320;
        float s1a = 0.f, s1b = 0.f, s2a = 0.f, s2b = 0.f;
        for (int k = 0; k < D_; k += 4) {
            const float4 pv = *(const float4*)&prow[k];          // wave-uniform broadcast
            const float* w = W1 + (size_t)k * H1_;
            s1a = fmaf(pv.x, w[j1],            s1a);
            s1b = fmaf(pv.y, w[H1_ + j1],      s1b);
            s1a = fmaf(pv.z, w[2 * H1_ + j1],  s1a);
            s1b = fmaf(pv.w, w[3 * H1_ + j1],  s1b);
            s2a = fmaf(pv.x, w[j2],            s2a);
            s2b = fmaf(pv.y, w[H1_ + j2],      s2b);
            s2a = fmaf(pv.z, w[2 * H1_ + j2],  s2a);
            s2b = fmaf(pv.w, w[3 * H1_ + j2],  s2b);
        }
        hrow[j1] = fmaxf(s1a + s1b + b1[j1], 0.f);
        hrow[j2] = fmaxf(s2a + s2b + b1[j2], 0.f);
    }
    __syncthreads();

    // ---- Phase C: erow = relu(hrow @ W2 + b2); thread owns col tid ----
    {
        const int j = tid;
        float a0 = 0.f, a1 = 0.f;
        for (int k = 0; k < H1_; k += 4) {
            const float4 hv = *(const float4*)&hrow[k];
            const float* w = W2 + (size_t)k * H2_ + j;
            a0 = fmaf(hv.x, w[0],        a0);
            a1 = fmaf(hv.y, w[H2_],      a1);
            a0 = fmaf(hv.z, w[2 * H2_],  a0);
            a1 = fmaf(hv.w, w[3 * H2_],  a1);
        }
        const float e = fmaxf(a0 + a1 + b2[j], 0.f);
        erow[j] = e;
        out[128 + (size_t)b * H2_ + j] = e;
    }
    __syncthreads();

    // ---- Phase D: y = erow @ W3 + b3 (two waves, shuffle reduce) ----
    if (tid < 128) {
        const int o = tid >> 6, lane = tid & 63;
        float s = 0.f;
        for (int j = lane; j < H2_; j += 64)
            s = fmaf(erow[j], W3[(size_t)j * 2 + o], s);
        #pragma unroll
        for (int off = 32; off >= 1; off >>= 1)
            s += __shfl_down(s, off, 64);
        if (lane == 0) out[(size_t)b * 2 + o] = s + b3[o];
    }
}

extern "C" void kernel_launch(void* const* d_in, const int* in_sizes, int n_in,
                              void* d_out, int out_size, void* d_ws, size_t ws_size,
                              hipStream_t stream) {
    const float* rep  = (const float*)d_in[0];
    const int*   blen = (const int*)  d_in[1];
    const float* W1   = (const float*)d_in[2];
    const float* b1   = (const float*)d_in[3];
    const float* W2   = (const float*)d_in[4];
    const float* b2   = (const float*)d_in[5];
    const float* W3   = (const float*)d_in[6];
    const float* b3   = (const float*)d_in[7];
    float* out = (float*)d_out;

    // workspace: part = B_*NSPLIT*D_ floats (10.5 MB)
    float* part = (float*)d_ws;

    // TIMING PROBE: pool_partial launched twice (identical output).
    // dur_us(R8) - dur_us(R7) == pool_partial duration (+1 node gap).
    pool_partial<<<dim3(NSPLIT, B_), 320, 0, stream>>>(rep, blen, part);
    pool_partial<<<dim3(NSPLIT, B_), 320, 0, stream>>>(rep, blen, part);
    fused_tail  <<<B_, 320, 0, stream>>>(part, blen, W1, b1, W2, b2, W3, b3, out);
}